// Round 6
// baseline (325.260 us; speedup 1.0000x reference)
//
#include <hip/hip_runtime.h>
#include <hip/hip_cooperative_groups.h>
#include <hip/hip_bf16.h>

namespace cg = cooperative_groups;

typedef _Float16 f16;
typedef _Float16 h4 __attribute__((ext_vector_type(4)));
typedef float f32x4 __attribute__((ext_vector_type(4)));

#define B_   128
#define PP_  1024
#define LP_  128
#define H_   256
#define GRID_ 512

// Projected-table row layout in tbl (f16, 178 rows x 256):
//   PE rows 0..127   = Ee@Wd1
//   PA rows 128..159 = Ea@Wd1
//   PB rows 160..161 = Eb@Wd1 + bd1
//   PL rows 162..177 = El@Wd1 + bd1
// wc: [0..65535] WcP (k-major), [65536..131071] WcL.

__global__ void __launch_bounds__(256, 2) fused_k(
    const int* __restrict__ pel, const int* __restrict__ paa,
    const int* __restrict__ pbb, const int* __restrict__ ltyp,
    const float* __restrict__ ppos, const float* __restrict__ lpos,
    const float* __restrict__ Ee, const float* __restrict__ Ea,
    const float* __restrict__ Eb, const float* __restrict__ El,
    const float* __restrict__ W1, const float* __restrict__ bd1,
    const float* __restrict__ W2, const float* __restrict__ Wa1,
    const float* __restrict__ ba1, const float* __restrict__ bd2,
    const float* __restrict__ Wa2, const float* __restrict__ ba2,
    f16* __restrict__ tbl, float* __restrict__ wc,
    float* __restrict__ cvec, float* __restrict__ ysum,
    float* __restrict__ out)
{
  cg::grid_group grid = cg::this_grid();
  const int bid = blockIdx.x, tid = threadIdx.x;
  const int wave = tid >> 6, lane = tid & 63;

  __shared__ float src[256];
  __shared__ float px[4 * 264], py[4 * 264], pz[4 * 264];
  __shared__ float lmin[128];
  __shared__ float ysc[512];
  __shared__ float cls[2];
  __shared__ float red[4];

  // ================= phase 1: prep (zero ysum; project tables; collapse Wd2@Wa1)
  if (bid < 256) ysum[bid * 256 + tid] = 0.f;

#pragma unroll 1
  for (int jj = 0; jj < 2; ++jj) {
    const int j = bid + jj * GRID_;
    if (j >= 691) break;
    if (jj) __syncthreads();   // src reuse
    if (j < 178) {
      const float* s;
      float badd = 0.f;
      if (j < 128)      s = Ee + j * 256;
      else if (j < 160) s = Ea + (j - 128) * 256;
      else if (j < 162) { s = Eb + (j - 160) * 256; badd = bd1[tid]; }
      else              { s = El + (j - 162) * 256; badd = bd1[tid]; }
      src[tid] = s[tid];
      __syncthreads();
      float a0 = 0.f, a1 = 0.f, a2 = 0.f, a3 = 0.f;
#pragma unroll 4
      for (int k = 0; k < 256; k += 4) {
        a0 += src[k]     * W1[(k)     * 256 + tid];
        a1 += src[k + 1] * W1[(k + 1) * 256 + tid];
        a2 += src[k + 2] * W1[(k + 2) * 256 + tid];
        a3 += src[k + 3] * W1[(k + 3) * 256 + tid];
      }
      tbl[j * 256 + tid] = (f16)(((a0 + a1) + (a2 + a3)) + badd);
    } else if (j < 690) {
      const int r = j - 178;
      const int half = r >> 8, rr = r & 255;
      src[tid] = W2[rr * 256 + tid];
      __syncthreads();
      const float* W = Wa1 + half * 256 * 256 + tid;
      float a0 = 0.f, a1 = 0.f, a2 = 0.f, a3 = 0.f;
#pragma unroll 4
      for (int n = 0; n < 256; n += 4) {
        a0 += src[n]     * W[(n)     * 256];
        a1 += src[n + 1] * W[(n + 1) * 256];
        a2 += src[n + 2] * W[(n + 2) * 256];
        a3 += src[n + 3] * W[(n + 3) * 256];
      }
      const float scale = half ? (1.f / (float)LP_) : (1.f / (float)PP_);
      wc[half * 65536 + rr * 256 + tid] = ((a0 + a1) + (a2 + a3)) * scale;
    } else {
      float a = ba1[tid];
#pragma unroll 8
      for (int n = 0; n < 256; ++n)
        a += bd2[n] * (Wa1[n * 256 + tid] + Wa1[(256 + n) * 256 + tid]);
      cvec[tid] = a;
    }
  }

  grid.sync();

  // ================= phase 2: gather + silu + batch colsum (per-wave atomics)
  {
    const int c0 = lane * 4;
    // 4 protein jobs: pj = bid + k*512 -> batch = pj>>4, group g = pj&15 (64 rows)
#pragma unroll 1
    for (int k = 0; k < 4; ++k) {
      const int pj = bid + k * GRID_;
      const int batch = pj >> 4, g = pj & 15;
      const int base = batch * PP_ + g * 64 + wave * 16;
      f32x4 acc = (f32x4){0.f, 0.f, 0.f, 0.f};
#pragma unroll 4
      for (int r = 0; r < 16; ++r) {
        const int idx = base + r;
        h4 va = *(const h4*)(tbl + pel[idx] * 256 + c0);
        h4 vb = *(const h4*)(tbl + 32768 + paa[idx] * 256 + c0);
        h4 vc = *(const h4*)(tbl + 40960 + pbb[idx] * 256 + c0);
        h4 s = va + vb + vc;   // packed f16 adds
#pragma unroll
        for (int i = 0; i < 4; ++i) {
          float pre = (float)s[i];
          acc[i] += pre * __builtin_amdgcn_rcpf(1.f + __expf(-pre));
        }
      }
      float* pool = ysum + batch * 256 + c0;
#pragma unroll
      for (int i = 0; i < 4; ++i) atomicAdd(pool + i, acc[i]);
    }
    // 1 ligand job: batch = bid>>2, lg = bid&3 (32 rows, wave does 8)
    {
      const int batch = bid >> 2, lg = bid & 3;
      const int base = batch * LP_ + lg * 32 + wave * 8;
      f32x4 acc = (f32x4){0.f, 0.f, 0.f, 0.f};
#pragma unroll 4
      for (int r = 0; r < 8; ++r) {
        h4 v = *(const h4*)(tbl + 41472 + ltyp[base + r] * 256 + c0);
#pragma unroll
        for (int i = 0; i < 4; ++i) {
          float pre = (float)v[i];
          acc[i] += pre * __builtin_amdgcn_rcpf(1.f + __expf(-pre));
        }
      }
      float* pool = ysum + 32768 + batch * 256 + c0;
#pragma unroll
      for (int i = 0; i < 4; ++i) atomicAdd(pool + i, acc[i]);
    }
  }

  grid.sync();

  // ================= phase 3: contact + collapsed matvec + affinity (blocks 0..127)
  if (bid >= B_) return;
  const int b = bid;

#pragma unroll
  for (int r = 0; r < 4; ++r) {
    const int i = r * 256 + tid;
    const int d = (i >> 8) * 264 + (i & 255);
    const float* p = ppos + ((size_t)b * PP_ + i) * 3;
    px[d] = p[0]; py[d] = p[1]; pz[d] = p[2];
  }
  ysc[tid] = ysum[b * 256 + tid];
  ysc[256 + tid] = ysum[32768 + b * 256 + tid];
  __syncthreads();

  // contact: 2 threads per ligand, 512 points each from padded LDS
  {
    const int lig = tid >> 1, prt = tid & 1;
    const float* lp = lpos + ((size_t)b * LP_ + lig) * 3;
    const float lx = lp[0], ly = lp[1], lz = lp[2];
    float m = 3.4e38f;
#pragma unroll 1
    for (int s2 = prt * 2; s2 < prt * 2 + 2; ++s2) {
      const float4* X4 = (const float4*)(px + s2 * 264);
      const float4* Y4 = (const float4*)(py + s2 * 264);
      const float4* Z4 = (const float4*)(pz + s2 * 264);
#pragma unroll 4
      for (int i = 0; i < 64; ++i) {
        float4 X = X4[i], Y = Y4[i], Z = Z4[i];
        float dx, dy, dz, d2;
        dx = lx - X.x; dy = ly - Y.x; dz = lz - Z.x;
        d2 = dx * dx + dy * dy + dz * dz; m = fminf(m, d2);
        dx = lx - X.y; dy = ly - Y.y; dz = lz - Z.y;
        d2 = dx * dx + dy * dy + dz * dz; m = fminf(m, d2);
        dx = lx - X.z; dy = ly - Y.z; dz = lz - Z.z;
        d2 = dx * dx + dy * dy + dz * dz; m = fminf(m, d2);
        dx = lx - X.w; dy = ly - Y.w; dz = lz - Z.w;
        d2 = dx * dx + dy * dy + dz * dz; m = fminf(m, d2);
      }
    }
    m = fminf(m, __shfl_xor(m, 1));
    if (prt == 0) lmin[lig] = sqrtf(m);
  }
  __syncthreads();
  if (tid < 64) {
    const float a0 = lmin[tid], a1 = lmin[tid + 64];
    float sm = a0 + a1, mn = fminf(a0, a1);
#pragma unroll
    for (int off = 32; off; off >>= 1) {
      sm += __shfl_down(sm, off);
      mn = fminf(mn, __shfl_down(mn, off));
    }
    if (tid == 0) { cls[0] = sm * (1.f / (float)LP_); cls[1] = mn; }
  }

  // matvec: thread = output col j, full K = 512 (WcP then WcL)
  float mv;
  {
    const int j = tid;
    float a[8];
#pragma unroll
    for (int u = 0; u < 8; ++u) a[u] = 0.f;
#pragma unroll 2
    for (int k = 0; k < 256; k += 8) {
#pragma unroll
      for (int u = 0; u < 8; ++u)
        a[u] += ysc[k + u] * wc[(k + u) * 256 + j];
    }
#pragma unroll 2
    for (int k = 0; k < 256; k += 8) {
#pragma unroll
      for (int u = 0; u < 8; ++u)
        a[u] += ysc[256 + k + u] * wc[65536 + (k + u) * 256 + j];
    }
    mv = ((a[0] + a[1]) + (a[2] + a[3])) + ((a[4] + a[5]) + (a[6] + a[7]));
  }
  __syncthreads();

  {
    float pre = mv + cvec[tid]
              + cls[0] * Wa1[512 * 256 + tid] + cls[1] * Wa1[513 * 256 + tid];
    float si = pre * __builtin_amdgcn_rcpf(1.f + __expf(-pre));
    float p = si * Wa2[tid];
#pragma unroll
    for (int off = 32; off; off >>= 1) p += __shfl_down(p, off);
    if ((tid & 63) == 0) red[tid >> 6] = p;
  }
  __syncthreads();
  if (tid == 0) out[b] = (red[0] + red[1]) + (red[2] + red[3]) + ba2[0];
}

// ---------------------------------------------------------------- launch
extern "C" void kernel_launch(void* const* d_in, const int* in_sizes, int n_in,
                              void* d_out, int out_size, void* d_ws, size_t ws_size,
                              hipStream_t stream)
{
  const float* protein_pos = (const float*)d_in[0];
  const float* ligand_pos  = (const float*)d_in[1];
  const int*   pel  = (const int*)d_in[2];
  const int*   paa  = (const int*)d_in[3];
  const int*   pbb  = (const int*)d_in[4];
  const int*   ltyp = (const int*)d_in[5];
  const float* Ee  = (const float*)d_in[8];
  const float* Ea  = (const float*)d_in[9];
  const float* Eb  = (const float*)d_in[10];
  const float* El  = (const float*)d_in[11];
  const float* Wd1 = (const float*)d_in[12];
  const float* bd1 = (const float*)d_in[13];
  const float* Wd2 = (const float*)d_in[14];
  const float* bd2 = (const float*)d_in[15];
  const float* Wa1 = (const float*)d_in[16];
  const float* ba1 = (const float*)d_in[17];
  const float* Wa2 = (const float*)d_in[18];
  const float* ba2 = (const float*)d_in[19];
  float* out = (float*)d_out;

  char* ws = (char*)d_ws;
  f16*   tbl  = (f16*)(ws);                  // 178*256 f16 = 91136 B
  float* ysum = (float*)(ws + 98304);        // 65536 f32 = 262144 B
  float* wc   = (float*)(ws + 360448);       // 131072 f32 = 524288 B
  float* cvec = (float*)(ws + 884736);       // 1024 B

  void* args[] = {
    (void*)&pel, (void*)&paa, (void*)&pbb, (void*)&ltyp,
    (void*)&protein_pos, (void*)&ligand_pos,
    (void*)&Ee, (void*)&Ea, (void*)&Eb, (void*)&El,
    (void*)&Wd1, (void*)&bd1, (void*)&Wd2, (void*)&Wa1,
    (void*)&ba1, (void*)&bd2, (void*)&Wa2, (void*)&ba2,
    (void*)&tbl, (void*)&wc, (void*)&cvec, (void*)&ysum, (void*)&out
  };
  hipLaunchCooperativeKernel((const void*)fused_k, dim3(GRID_), dim3(256),
                             args, 0, stream);
}

// Round 7
// 150.785 us; speedup vs baseline: 2.1571x; 2.1571x over previous
//
#include <hip/hip_runtime.h>
#include <hip/hip_bf16.h>

typedef _Float16 f16;
typedef _Float16 h2 __attribute__((ext_vector_type(2)));

#define B_   128
#define PP_  1024
#define LP_  128
#define H_   256

// tbl rows (f16, 178 x 256): PE 0..127 = Ee@Wd1; PA 128..159 = Ea@Wd1;
// PB 160..161 = Eb@Wd1 + bd1; PL 162..177 = El@Wd1 + bd1.

// ---------------------------------------------------------------- kernel A
// bid 0..177: project one embedding row through Wd1 -> f16 tbl row.
// bid 178..305: contact features for batch b = bid-178 -> cbuf[b*2..].
__global__ void __launch_bounds__(256) prep_k(
    const float* __restrict__ W1,
    const float* __restrict__ Ee, const float* __restrict__ Ea,
    const float* __restrict__ Eb, const float* __restrict__ El,
    const float* __restrict__ bd1,
    const float* __restrict__ ppos, const float* __restrict__ lpos,
    f16* __restrict__ tbl, float* __restrict__ cbuf)
{
  __shared__ float px[4 * 264], py[4 * 264], pz[4 * 264];
  __shared__ float lmin[128];
  __shared__ float src[256];
  const int bid = blockIdx.x, tid = threadIdx.x;

  if (bid < 178) {
    const float* s;
    float badd = 0.f;
    if (bid < 128)      s = Ee + bid * 256;
    else if (bid < 160) s = Ea + (bid - 128) * 256;
    else if (bid < 162) { s = Eb + (bid - 160) * 256; badd = bd1[tid]; }
    else                { s = El + (bid - 162) * 256; badd = bd1[tid]; }
    src[tid] = s[tid];
    __syncthreads();
    float a0 = 0.f, a1 = 0.f, a2 = 0.f, a3 = 0.f;
#pragma unroll 4
    for (int k = 0; k < 256; k += 4) {
      a0 += src[k]     * W1[(k)     * 256 + tid];
      a1 += src[k + 1] * W1[(k + 1) * 256 + tid];
      a2 += src[k + 2] * W1[(k + 2) * 256 + tid];
      a3 += src[k + 3] * W1[(k + 3) * 256 + tid];
    }
    tbl[bid * 256 + tid] = (f16)(((a0 + a1) + (a2 + a3)) + badd);
    return;
  }

  // ---- contact for batch b
  const int b = bid - 178;
#pragma unroll
  for (int r = 0; r < 4; ++r) {
    const int i = r * 256 + tid;
    const int d = (i >> 8) * 264 + (i & 255);
    const float* p = ppos + ((size_t)b * PP_ + i) * 3;
    px[d] = p[0]; py[d] = p[1]; pz[d] = p[2];
  }
  __syncthreads();
  {
    const int lig = tid >> 1, prt = tid & 1;
    const float* lp = lpos + ((size_t)b * LP_ + lig) * 3;
    const float lx = lp[0], ly = lp[1], lz = lp[2];
    float m = 3.4e38f;
#pragma unroll 1
    for (int s2 = prt * 2; s2 < prt * 2 + 2; ++s2) {
      const float4* X4 = (const float4*)(px + s2 * 264);
      const float4* Y4 = (const float4*)(py + s2 * 264);
      const float4* Z4 = (const float4*)(pz + s2 * 264);
#pragma unroll 4
      for (int i = 0; i < 64; ++i) {
        float4 X = X4[i], Y = Y4[i], Z = Z4[i];
        float dx, dy, dz, d2;
        dx = lx - X.x; dy = ly - Y.x; dz = lz - Z.x;
        d2 = dx * dx + dy * dy + dz * dz; m = fminf(m, d2);
        dx = lx - X.y; dy = ly - Y.y; dz = lz - Z.y;
        d2 = dx * dx + dy * dy + dz * dz; m = fminf(m, d2);
        dx = lx - X.z; dy = ly - Y.z; dz = lz - Z.z;
        d2 = dx * dx + dy * dy + dz * dz; m = fminf(m, d2);
        dx = lx - X.w; dy = ly - Y.w; dz = lz - Z.w;
        d2 = dx * dx + dy * dy + dz * dz; m = fminf(m, d2);
      }
    }
    m = fminf(m, __shfl_xor(m, 1));
    if (prt == 0) lmin[lig] = sqrtf(m);
  }
  __syncthreads();
  if (tid < 64) {
    const float a0 = lmin[tid], a1 = lmin[tid + 64];
    float sm = a0 + a1, mn = fminf(a0, a1);
#pragma unroll
    for (int off = 32; off; off >>= 1) {
      sm += __shfl_down(sm, off);
      mn = fminf(mn, __shfl_down(mn, off));
    }
    if (tid == 0) {
      cbuf[b * 2 + 0] = sm * (1.f / (float)LP_);
      cbuf[b * 2 + 1] = mn;
    }
  }
}

// ---------------------------------------------------------------- kernel B
// One 1024-thread block per batch. Phase 1: gather+silu+column-sum its batch's
// 1024 P rows + 128 L rows (thread = (col-pair, row-group), LDS tree-reduce —
// no atomics, no global pool buffer). Phase 2: pooled = ys@Wd2/cnt + bd2;
// pre = ba1 + pooledP@Wa1_P + pooledL@Wa1_L + contact terms;
// out = silu(pre)@Wa2 + ba2.
__global__ void __launch_bounds__(1024) pool_head_k(
    const int* __restrict__ pel, const int* __restrict__ paa,
    const int* __restrict__ pbb, const int* __restrict__ ltyp,
    const f16* __restrict__ tbl, const float* __restrict__ cbuf,
    const float* __restrict__ W2, const float* __restrict__ bd2,
    const float* __restrict__ Wa1, const float* __restrict__ ba1,
    const float* __restrict__ Wa2, const float* __restrict__ ba2,
    float* __restrict__ out)
{
  __shared__ float redP[8][256];
  __shared__ float redL[8][256];
  __shared__ float ys[512];      // ysP | ysL (column sums)
  __shared__ float pooled[512];  // pooledP | pooledL
  __shared__ float part[512];
  __shared__ float red[4];
  const int b = blockIdx.x, tid = threadIdx.x;
  const int c2 = tid & 127;      // col pair: cols 2*c2, 2*c2+1
  const int rg = tid >> 7;       // row group 0..7

  // ---- phase 1: gather + silu + colsum
  float aP0 = 0.f, aP1 = 0.f, aL0 = 0.f, aL1 = 0.f;
  {
    const int pbase = b * PP_ + rg * 128;
#pragma unroll 4
    for (int r = 0; r < 128; ++r) {
      const int idx = pbase + r;
      h2 va = *(const h2*)(tbl + pel[idx] * 256 + c2 * 2);
      h2 vb = *(const h2*)(tbl + 32768 + paa[idx] * 256 + c2 * 2);
      h2 vc = *(const h2*)(tbl + 40960 + pbb[idx] * 256 + c2 * 2);
      h2 s = va + vb + vc;
      float p0 = (float)s[0], p1 = (float)s[1];
      aP0 += p0 * __builtin_amdgcn_rcpf(1.f + __expf(-p0));
      aP1 += p1 * __builtin_amdgcn_rcpf(1.f + __expf(-p1));
    }
    const int lbase = b * LP_ + rg * 16;
#pragma unroll 4
    for (int r = 0; r < 16; ++r) {
      h2 v = *(const h2*)(tbl + 41472 + ltyp[lbase + r] * 256 + c2 * 2);
      float p0 = (float)v[0], p1 = (float)v[1];
      aL0 += p0 * __builtin_amdgcn_rcpf(1.f + __expf(-p0));
      aL1 += p1 * __builtin_amdgcn_rcpf(1.f + __expf(-p1));
    }
  }
  redP[rg][c2 * 2] = aP0; redP[rg][c2 * 2 + 1] = aP1;
  redL[rg][c2 * 2] = aL0; redL[rg][c2 * 2 + 1] = aL1;
  __syncthreads();

  if (tid < 512) {
    const int h = tid >> 8, c = tid & 255;
    float s = 0.f;
    if (h == 0) {
#pragma unroll
      for (int g = 0; g < 8; ++g) s += redP[g][c];
    } else {
#pragma unroll
      for (int g = 0; g < 8; ++g) s += redL[g][c];
    }
    ys[h * 256 + c] = s;
  }
  __syncthreads();

  // ---- phase 2a: pooled = ys@Wd2 * (1/cnt) + bd2   (threads 0..511)
  if (tid < 512) {
    const int h = tid >> 8, n = tid & 255;
    const float* y = ys + h * 256;
    float a0 = 0.f, a1 = 0.f, a2 = 0.f, a3 = 0.f;
#pragma unroll 4
    for (int k = 0; k < 256; k += 4) {
      a0 += y[k]     * W2[(k)     * 256 + n];
      a1 += y[k + 1] * W2[(k + 1) * 256 + n];
      a2 += y[k + 2] * W2[(k + 2) * 256 + n];
      a3 += y[k + 3] * W2[(k + 3) * 256 + n];
    }
    const float scale = h ? (1.f / (float)LP_) : (1.f / (float)PP_);
    pooled[tid] = ((a0 + a1) + (a2 + a3)) * scale + bd2[n];
  }
  __syncthreads();

  // ---- phase 2b: pre partials over Wa1 (threads 0..511: (k-half, j))
  if (tid < 512) {
    const int kh = tid >> 8, j = tid & 255;
    const float* W = Wa1 + kh * 256 * 256 + j;
    const float* p = pooled + kh * 256;
    float a0 = 0.f, a1 = 0.f, a2 = 0.f, a3 = 0.f;
#pragma unroll 4
    for (int n = 0; n < 256; n += 4) {
      a0 += p[n]     * W[(n)     * 256];
      a1 += p[n + 1] * W[(n + 1) * 256];
      a2 += p[n + 2] * W[(n + 2) * 256];
      a3 += p[n + 3] * W[(n + 3) * 256];
    }
    part[tid] = (a0 + a1) + (a2 + a3);
  }
  __syncthreads();

  if (tid < 256) {
    const float c0 = cbuf[b * 2], c1 = cbuf[b * 2 + 1];
    float pre = part[tid] + part[256 + tid] + ba1[tid]
              + c0 * Wa1[512 * 256 + tid] + c1 * Wa1[513 * 256 + tid];
    float si = pre * __builtin_amdgcn_rcpf(1.f + __expf(-pre));
    float p = si * Wa2[tid];
#pragma unroll
    for (int off = 32; off; off >>= 1) p += __shfl_down(p, off);
    if ((tid & 63) == 0) red[tid >> 6] = p;
  }
  __syncthreads();
  if (tid == 0) out[b] = (red[0] + red[1]) + (red[2] + red[3]) + ba2[0];
}

// ---------------------------------------------------------------- launch
extern "C" void kernel_launch(void* const* d_in, const int* in_sizes, int n_in,
                              void* d_out, int out_size, void* d_ws, size_t ws_size,
                              hipStream_t stream)
{
  const float* protein_pos = (const float*)d_in[0];
  const float* ligand_pos  = (const float*)d_in[1];
  const int*   pel  = (const int*)d_in[2];
  const int*   paa  = (const int*)d_in[3];
  const int*   pbb  = (const int*)d_in[4];
  const int*   ltyp = (const int*)d_in[5];
  const float* Ee  = (const float*)d_in[8];
  const float* Ea  = (const float*)d_in[9];
  const float* Eb  = (const float*)d_in[10];
  const float* El  = (const float*)d_in[11];
  const float* Wd1 = (const float*)d_in[12];
  const float* bd1 = (const float*)d_in[13];
  const float* Wd2 = (const float*)d_in[14];
  const float* bd2 = (const float*)d_in[15];
  const float* Wa1 = (const float*)d_in[16];
  const float* ba1 = (const float*)d_in[17];
  const float* Wa2 = (const float*)d_in[18];
  const float* ba2 = (const float*)d_in[19];
  float* out = (float*)d_out;

  char* ws = (char*)d_ws;
  f16*   tbl  = (f16*)(ws);             // 178*256 f16 = 91136 B
  float* cbuf = (float*)(ws + 98304);   // 256 f32 = 1024 B

  prep_k<<<306, 256, 0, stream>>>(Wd1, Ee, Ea, Eb, El, bd1,
                                  protein_pos, ligand_pos, tbl, cbuf);
  pool_head_k<<<B_, 1024, 0, stream>>>(pel, paa, pbb, ltyp, tbl, cbuf,
                                       Wd2, bd2, Wa1, ba1, Wa2, ba2, out);
}

// Round 8
// 141.292 us; speedup vs baseline: 2.3020x; 1.0672x over previous
//
#include <hip/hip_runtime.h>
#include <hip/hip_bf16.h>

typedef _Float16 f16;
typedef _Float16 h4 __attribute__((ext_vector_type(4)));

#define B_   128
#define PP_  1024
#define LP_  128
#define H_   256

// tbl rows (f16, 178 x 256): PE 0..127 = Ee@Wd1; PA 128..159 = Ea@Wd1;
// PB 160..161 = Eb@Wd1 + bd1; PL 162..177 = El@Wd1 + bd1.
// ysum: [0,32768) P pools, [32768,65536) L pools (both 128 batches x 256).

// ---------------------------------------------------------------- kernel A
// bid 0..177: project one embedding row through Wd1 -> f16 tbl row.
// bid 178..305: contact features for batch b = bid-178 -> cbuf.
// bids 0..255 also zero ysum (re-poisoned to 0xAA before every launch).
__global__ void __launch_bounds__(256) prep_k(
    const float* __restrict__ W1,
    const float* __restrict__ Ee, const float* __restrict__ Ea,
    const float* __restrict__ Eb, const float* __restrict__ El,
    const float* __restrict__ bd1,
    const float* __restrict__ ppos, const float* __restrict__ lpos,
    f16* __restrict__ tbl, float* __restrict__ cbuf, float* __restrict__ ysum)
{
  __shared__ float px[4 * 264], py[4 * 264], pz[4 * 264];
  __shared__ float lmin[128];
  __shared__ float src[256];
  const int bid = blockIdx.x, tid = threadIdx.x;
  if (bid < 256) ysum[bid * 256 + tid] = 0.f;

  if (bid < 178) {
    const float* s;
    float badd = 0.f;
    if (bid < 128)      s = Ee + bid * 256;
    else if (bid < 160) s = Ea + (bid - 128) * 256;
    else if (bid < 162) { s = Eb + (bid - 160) * 256; badd = bd1[tid]; }
    else                { s = El + (bid - 162) * 256; badd = bd1[tid]; }
    src[tid] = s[tid];
    __syncthreads();
    float a0 = 0.f, a1 = 0.f, a2 = 0.f, a3 = 0.f;
#pragma unroll 4
    for (int k = 0; k < 256; k += 4) {
      a0 += src[k]     * W1[(k)     * 256 + tid];
      a1 += src[k + 1] * W1[(k + 1) * 256 + tid];
      a2 += src[k + 2] * W1[(k + 2) * 256 + tid];
      a3 += src[k + 3] * W1[(k + 3) * 256 + tid];
    }
    tbl[bid * 256 + tid] = (f16)(((a0 + a1) + (a2 + a3)) + badd);
    return;
  }

  // ---- contact for batch b
  const int b = bid - 178;
#pragma unroll
  for (int r = 0; r < 4; ++r) {
    const int i = r * 256 + tid;
    const int d = (i >> 8) * 264 + (i & 255);
    const float* p = ppos + ((size_t)b * PP_ + i) * 3;
    px[d] = p[0]; py[d] = p[1]; pz[d] = p[2];
  }
  __syncthreads();
  {
    const int lig = tid >> 1, prt = tid & 1;
    const float* lp = lpos + ((size_t)b * LP_ + lig) * 3;
    const float lx = lp[0], ly = lp[1], lz = lp[2];
    float m = 3.4e38f;
#pragma unroll 1
    for (int s2 = prt * 2; s2 < prt * 2 + 2; ++s2) {
      const float4* X4 = (const float4*)(px + s2 * 264);
      const float4* Y4 = (const float4*)(py + s2 * 264);
      const float4* Z4 = (const float4*)(pz + s2 * 264);
#pragma unroll 4
      for (int i = 0; i < 64; ++i) {
        float4 X = X4[i], Y = Y4[i], Z = Z4[i];
        float dx, dy, dz, d2;
        dx = lx - X.x; dy = ly - Y.x; dz = lz - Z.x;
        d2 = dx * dx + dy * dy + dz * dz; m = fminf(m, d2);
        dx = lx - X.y; dy = ly - Y.y; dz = lz - Z.y;
        d2 = dx * dx + dy * dy + dz * dz; m = fminf(m, d2);
        dx = lx - X.z; dy = ly - Y.z; dz = lz - Z.z;
        d2 = dx * dx + dy * dy + dz * dz; m = fminf(m, d2);
        dx = lx - X.w; dy = ly - Y.w; dz = lz - Z.w;
        d2 = dx * dx + dy * dy + dz * dz; m = fminf(m, d2);
      }
    }
    m = fminf(m, __shfl_xor(m, 1));
    if (prt == 0) lmin[lig] = sqrtf(m);
  }
  __syncthreads();
  if (tid < 64) {
    const float a0 = lmin[tid], a1 = lmin[tid + 64];
    float sm = a0 + a1, mn = fminf(a0, a1);
#pragma unroll
    for (int off = 32; off; off >>= 1) {
      sm += __shfl_down(sm, off);
      mn = fminf(mn, __shfl_down(mn, off));
    }
    if (tid == 0) {
      cbuf[b * 2 + 0] = sm * (1.f / (float)LP_);
      cbuf[b * 2 + 1] = mn;
    }
  }
}

// ---------------------------------------------------------------- kernel B
// Block = (batch, g): g<8 -> 128 protein rows, g==8 -> 128 ligand rows.
// Wave owns 32 rows; lane owns 4 cols (h4). Index bases forced scalar via
// readfirstlane -> s_load chunks; 24 gathers/chunk issued before use (ILP).
__global__ void __launch_bounds__(256, 4) gpool_k(
    const int* __restrict__ pel, const int* __restrict__ paa,
    const int* __restrict__ pbb, const int* __restrict__ ltyp,
    const f16* __restrict__ tbl, float* __restrict__ ysum)
{
  const int tid = threadIdx.x;
  const int wave = __builtin_amdgcn_readfirstlane(tid >> 6);
  const int lane = tid & 63;
  const int batch = blockIdx.x / 9, g = blockIdx.x % 9;
  const int c0 = lane * 4;
  float acc[4] = {0.f, 0.f, 0.f, 0.f};

  if (g < 8) {
    const int base = batch * PP_ + g * 128 + wave * 32;
#pragma unroll
    for (int ch = 0; ch < 4; ++ch) {
      const int cb = base + ch * 8;
      const int4 e0 = *(const int4*)(pel + cb), e1 = *(const int4*)(pel + cb + 4);
      const int4 a0 = *(const int4*)(paa + cb), a1 = *(const int4*)(paa + cb + 4);
      const int4 b0 = *(const int4*)(pbb + cb), b1 = *(const int4*)(pbb + cb + 4);
      const int el[8] = {e0.x, e0.y, e0.z, e0.w, e1.x, e1.y, e1.z, e1.w};
      const int aa[8] = {a0.x, a0.y, a0.z, a0.w, a1.x, a1.y, a1.z, a1.w};
      const int bb[8] = {b0.x, b0.y, b0.z, b0.w, b1.x, b1.y, b1.z, b1.w};
      h4 s[8];
#pragma unroll
      for (int r = 0; r < 8; ++r) {
        h4 va = *(const h4*)(tbl + el[r] * 256 + c0);
        h4 vb = *(const h4*)(tbl + 32768 + aa[r] * 256 + c0);
        h4 vc = *(const h4*)(tbl + 40960 + bb[r] * 256 + c0);
        s[r] = (va + vb) + vc;
      }
#pragma unroll
      for (int r = 0; r < 8; ++r)
#pragma unroll
        for (int i = 0; i < 4; ++i) {
          float pre = (float)s[r][i];
          acc[i] += pre * __builtin_amdgcn_rcpf(1.f + __expf(-pre));
        }
    }
    float* pool = ysum + batch * 256 + c0;
#pragma unroll
    for (int i = 0; i < 4; ++i) atomicAdd(pool + i, acc[i]);
  } else {
    const int base = batch * LP_ + wave * 32;
#pragma unroll
    for (int ch = 0; ch < 4; ++ch) {
      const int cb = base + ch * 8;
      const int4 l0 = *(const int4*)(ltyp + cb), l1 = *(const int4*)(ltyp + cb + 4);
      const int lt[8] = {l0.x, l0.y, l0.z, l0.w, l1.x, l1.y, l1.z, l1.w};
      h4 s[8];
#pragma unroll
      for (int r = 0; r < 8; ++r)
        s[r] = *(const h4*)(tbl + 41472 + lt[r] * 256 + c0);
#pragma unroll
      for (int r = 0; r < 8; ++r)
#pragma unroll
        for (int i = 0; i < 4; ++i) {
          float pre = (float)s[r][i];
          acc[i] += pre * __builtin_amdgcn_rcpf(1.f + __expf(-pre));
        }
    }
    float* pool = ysum + 32768 + batch * 256 + c0;
#pragma unroll
    for (int i = 0; i < 4; ++i) atomicAdd(pool + i, acc[i]);
  }
}

// ---------------------------------------------------------------- kernel C
// One 1024-thread block per batch: pooled = ys@Wd2/cnt + bd2 (K split 2-way),
// pre = pooled@Wa1 (K split 4-way) + ba1 + contact terms; out = silu(pre)@Wa2+ba2.
__global__ void __launch_bounds__(1024) head_k(
    const float* __restrict__ ysum, const float* __restrict__ cbuf,
    const float* __restrict__ W2, const float* __restrict__ bd2,
    const float* __restrict__ Wa1, const float* __restrict__ ba1,
    const float* __restrict__ Wa2, const float* __restrict__ ba2,
    float* __restrict__ out)
{
  __shared__ float ys[512], pooled[512], p2[1024], part[1024], red[4];
  const int b = blockIdx.x, tid = threadIdx.x;

  if (tid < 512)
    ys[tid] = (tid < 256) ? ysum[b * 256 + tid]
                          : ysum[32768 + b * 256 + (tid - 256)];
  __syncthreads();

  // pooled partials: (kh2 = tid>>9, h = (tid>>8)&1, n = tid&255), 128-K slice
  {
    const int kh2 = tid >> 9, h = (tid >> 8) & 1, n = tid & 255;
    const float* y = ys + h * 256 + kh2 * 128;
    const float* W = W2 + kh2 * 128 * 256 + n;
    float a[8];
#pragma unroll
    for (int u = 0; u < 8; ++u) a[u] = 0.f;
#pragma unroll 2
    for (int k = 0; k < 128; k += 8)
#pragma unroll
      for (int u = 0; u < 8; ++u)
        a[u] += y[k + u] * W[(k + u) * 256];
    p2[tid] = ((a[0] + a[1]) + (a[2] + a[3])) + ((a[4] + a[5]) + (a[6] + a[7]));
  }
  __syncthreads();
  if (tid < 512) {
    const int h = tid >> 8, n = tid & 255;
    const float scale = h ? (1.f / (float)LP_) : (1.f / (float)PP_);
    pooled[tid] = (p2[tid] + p2[512 + tid]) * scale + bd2[n];
  }
  __syncthreads();

  // pre partials: (kq = tid>>8 in 0..3, j = tid&255), 128-N slice of Wa1
  {
    const int kq = tid >> 8, j = tid & 255;
    const float* p = pooled + kq * 128;
    const float* W = Wa1 + kq * 128 * 256 + j;
    float a[8];
#pragma unroll
    for (int u = 0; u < 8; ++u) a[u] = 0.f;
#pragma unroll 2
    for (int n = 0; n < 128; n += 8)
#pragma unroll
      for (int u = 0; u < 8; ++u)
        a[u] += p[n + u] * W[(n + u) * 256];
    part[tid] = ((a[0] + a[1]) + (a[2] + a[3])) + ((a[4] + a[5]) + (a[6] + a[7]));
  }
  __syncthreads();

  if (tid < 256) {
    const float c0 = cbuf[b * 2], c1 = cbuf[b * 2 + 1];
    float pre = (part[tid] + part[256 + tid]) + (part[512 + tid] + part[768 + tid])
              + ba1[tid] + c0 * Wa1[512 * 256 + tid] + c1 * Wa1[513 * 256 + tid];
    float si = pre * __builtin_amdgcn_rcpf(1.f + __expf(-pre));
    float p = si * Wa2[tid];
#pragma unroll
    for (int off = 32; off; off >>= 1) p += __shfl_down(p, off);
    if ((tid & 63) == 0) red[tid >> 6] = p;
  }
  __syncthreads();
  if (tid == 0) out[b] = (red[0] + red[1]) + (red[2] + red[3]) + ba2[0];
}

// ---------------------------------------------------------------- launch
extern "C" void kernel_launch(void* const* d_in, const int* in_sizes, int n_in,
                              void* d_out, int out_size, void* d_ws, size_t ws_size,
                              hipStream_t stream)
{
  const float* protein_pos = (const float*)d_in[0];
  const float* ligand_pos  = (const float*)d_in[1];
  const int*   pel  = (const int*)d_in[2];
  const int*   paa  = (const int*)d_in[3];
  const int*   pbb  = (const int*)d_in[4];
  const int*   ltyp = (const int*)d_in[5];
  const float* Ee  = (const float*)d_in[8];
  const float* Ea  = (const float*)d_in[9];
  const float* Eb  = (const float*)d_in[10];
  const float* El  = (const float*)d_in[11];
  const float* Wd1 = (const float*)d_in[12];
  const float* bd1 = (const float*)d_in[13];
  const float* Wd2 = (const float*)d_in[14];
  const float* bd2 = (const float*)d_in[15];
  const float* Wa1 = (const float*)d_in[16];
  const float* ba1 = (const float*)d_in[17];
  const float* Wa2 = (const float*)d_in[18];
  const float* ba2 = (const float*)d_in[19];
  float* out = (float*)d_out;

  char* ws = (char*)d_ws;
  f16*   tbl  = (f16*)(ws);              // 178*256 f16 = 91136 B
  float* cbuf = (float*)(ws + 98304);    // 1024 B
  float* ysum = (float*)(ws + 102400);   // 65536 f32 = 262144 B

  prep_k<<<306, 256, 0, stream>>>(Wd1, Ee, Ea, Eb, El, bd1,
                                  protein_pos, ligand_pos, tbl, cbuf, ysum);
  gpool_k<<<B_ * 9, 256, 0, stream>>>(pel, paa, pbb, ltyp, tbl, ysum);
  head_k<<<B_, 1024, 0, stream>>>(ysum, cbuf, Wd2, bd2, Wa1, ba1, Wa2, ba2, out);
}